// Round 5
// baseline (12.799 us; speedup 1.0000x reference)
//
#include <hip/hip_runtime.h>

// Bone/variance loss: B samples -> scalar.
// output: [B,1,64,64] f32, mask: [B,17] f32, ind: [B,17] int32, target: [B,17] f32, gt_2d: [B,17,2] f32
// out: [1] f32
//
// Round 5: SINGLE dispatch. Last-block-done finalize via monotonic ticket
// counter in d_ws: old = fetch_add(counter,1); finalizer iff old % nblk == nblk-1.
// nblk is a power of two and 2^32 % nblk == 0, so for ANY initial counter value
// (0xAA poison included) exactly one block per launch sees the finalizing
// residue, and this stays true across graph replays (no reset node needed).
// Final sum is read in fixed index order -> bitwise deterministic output.
// (Round 3 showed cooperative grid.sync costs +30us; this handoff is one-way.)

#define BLK 64

__global__ __launch_bounds__(BLK) void bone_fused(
    const float* __restrict__ out_hm,
    const float* __restrict__ mask,
    const int*   __restrict__ ind,
    const float* __restrict__ target,
    const float* __restrict__ gt2d,
    float* __restrict__ partial,
    unsigned*   counter,
    float* __restrict__ out,
    int B, int nblk, float invB)
{
    // Joints 7,9,10 appear in no bone: gather only the 14 used joints.
    constexpr int jl[14]   = {0,1,2,3,4,5,6,8,11,12,13,14,15,16};
    constexpr int id1[12]  = {3, 2, 4, 5, 16, 15, 11, 12, 1, 4, 14, 11};
    constexpr int id2[12]  = {2, 1, 5, 6, 15, 14, 12, 13, 0, 0,  8,  8};
    constexpr int gid[12]  = {0, 0, 0, 0,  1,  1,  1,  1, 2, 2,  3,  3};
    const float wbone[12]  = {1.0085885098415446f, 1.0f, 1.0f, 1.0085885098415446f,
                              1.1375361376887123f, 1.0f, 1.0f, 1.1375361376887123f,
                              1.0f, 1.0f, 1.0f, 1.0f};

    const int b = blockIdx.x * BLK + threadIdx.x;
    float per = 0.0f;
    if (b < B) {
        const float*  tb = target + (size_t)b * 17;
        const float*  mb = mask   + (size_t)b * 17;
        const int*    ib = ind    + (size_t)b * 17;
        const float2* gb = (const float2*)(gt2d + (size_t)b * 34);
        const float*  ob = out_hm + (size_t)b * 4096;

        // Long-latency scattered gathers first (14 independent loads).
        int idx[17];
        #pragma unroll
        for (int k = 0; k < 14; ++k) idx[jl[k]] = ib[jl[k]];
        float pr[17];
        #pragma unroll
        for (int k = 0; k < 14; ++k) pr[jl[k]] = ob[idx[jl[k]]];

        float t[17], gx[17], gy[17];
        #pragma unroll
        for (int k = 0; k < 14; ++k) t[jl[k]] = tb[jl[k]];
        #pragma unroll
        for (int k = 0; k < 14; ++k) {
            float2 g = gb[jl[k]];
            gx[jl[k]] = g.x; gy[jl[k]] = g.y;
        }
        float msum = 0.0f;
        #pragma unroll
        for (int j = 0; j < 17; ++j) msum += mb[j];

        float num[4] = {0,0,0,0}, sl[4] = {0,0,0,0};
        float l[12];
        bool  vis[12];
        #pragma unroll
        for (int k = 0; k < 12; ++k) {
            const int a = id1[k], c = id2[k];
            const bool v = (t[a] > 0.5f) && (t[c] > 0.5f);
            const float dx = gx[a] - gx[c];
            const float dy = gy[a] - gy[c];
            const float dp = pr[a] - pr[c];
            const float d2 = dx*dx + dy*dy + dp*dp;
            const float lv = v ? sqrtf(d2) * wbone[k] : 0.0f;
            vis[k] = v; l[k] = lv;
            num[gid[k]] += v ? 1.0f : 0.0f;
            sl[gid[k]]  += lv;
        }
        float E[4], dn[4];
        #pragma unroll
        for (int g = 0; g < 4; ++g) { dn[g] = fmaxf(num[g], 1.0f); E[g] = sl[g] / dn[g]; }
        #pragma unroll
        for (int k = 0; k < 12; ++k) {
            if (vis[k] && l[k] > 0.0f) {
                const float d = l[k] - E[gid[k]];
                per += d * d / (2.0f * dn[gid[k]]);
            }
        }
        if (msum != 0.0f) per = 0.0f;   // active = (mask.sum == 0)
    }

    // single-wave block: pure shuffle reduction
    #pragma unroll
    for (int off = 32; off > 0; off >>= 1) per += __shfl_down(per, off, 64);

    unsigned old = 0;
    if (threadIdx.x == 0) {
        // agent-scope release store of this block's partial, then ticket.
        __hip_atomic_store(&partial[blockIdx.x], per,
                           __ATOMIC_RELEASE, __HIP_MEMORY_SCOPE_AGENT);
        old = __hip_atomic_fetch_add(counter, 1u,
                                     __ATOMIC_ACQ_REL, __HIP_MEMORY_SCOPE_AGENT);
    }
    old = __shfl(old, 0, 64);

    if ((old & (unsigned)(nblk - 1)) == (unsigned)(nblk - 1)) {
        // this block arrived last: all partials are published. Fixed-order sum.
        __threadfence();   // acquire, device scope
        float s = 0.0f;
        for (int i = threadIdx.x; i < nblk; i += BLK)
            s += __hip_atomic_load(&partial[i],
                                   __ATOMIC_RELAXED, __HIP_MEMORY_SCOPE_AGENT);
        #pragma unroll
        for (int off = 32; off > 0; off >>= 1) s += __shfl_down(s, off, 64);
        if (threadIdx.x == 0) out[0] = s * invB;   // _VAR_WEIGHT == 1.0
    }
}

extern "C" void kernel_launch(void* const* d_in, const int* in_sizes, int n_in,
                              void* d_out, int out_size, void* d_ws, size_t ws_size,
                              hipStream_t stream)
{
    const float* output = (const float*)d_in[0];
    const float* mask   = (const float*)d_in[1];
    const int*   ind    = (const int*)  d_in[2];
    const float* target = (const float*)d_in[3];
    const float* gt2d   = (const float*)d_in[4];

    const int B = in_sizes[1] / 17;              // mask is [B,17]
    int nblk_raw = (B + BLK - 1) / BLK;          // 128 for B=8192
    int nblk = 1;
    while (nblk < nblk_raw) nblk <<= 1;          // pow2: residue trick needs 2^32 % nblk == 0

    float*    partial = (float*)d_ws;            // nblk floats
    unsigned* counter = (unsigned*)((char*)d_ws + (size_t)nblk * sizeof(float));

    bone_fused<<<nblk, BLK, 0, stream>>>(output, mask, ind, target, gt2d,
                                         partial, counter, (float*)d_out,
                                         B, nblk, 1.0f / (float)B);
}

// Round 6
// 12.130 us; speedup vs baseline: 1.0552x; 1.0552x over previous
//
#include <hip/hip_runtime.h>

// Bone/variance loss: B samples -> scalar.
// output: [B,1,64,64] f32, mask: [B,17] f32, ind: [B,17] int32, target: [B,17] f32, gt_2d: [B,17,2] f32
// out: [1] f32
//
// Round 6 = best structure (R2: two plain dispatches, 128 blk x 64 thr; coop
// grid.sync was +30us, single-dispatch atomic finalize was +1.9us) + best body
// (R5: joints 7,9,10 appear in no bone -> 14 gathers, fewer contiguous loads).
// Latency/overhead-bound: kernel exec ~2-3us, remainder is graph/dispatch floor.

#define BLK 64

__global__ __launch_bounds__(BLK) void bone_partial(
    const float* __restrict__ out_hm,
    const float* __restrict__ mask,
    const int*   __restrict__ ind,
    const float* __restrict__ target,
    const float* __restrict__ gt2d,
    float* __restrict__ partial, int B)
{
    // Only the 14 joints that participate in a bone.
    constexpr int jl[14]   = {0,1,2,3,4,5,6,8,11,12,13,14,15,16};
    constexpr int id1[12]  = {3, 2, 4, 5, 16, 15, 11, 12, 1, 4, 14, 11};
    constexpr int id2[12]  = {2, 1, 5, 6, 15, 14, 12, 13, 0, 0,  8,  8};
    constexpr int gid[12]  = {0, 0, 0, 0,  1,  1,  1,  1, 2, 2,  3,  3};
    const float wbone[12]  = {1.0085885098415446f, 1.0f, 1.0f, 1.0085885098415446f,
                              1.1375361376887123f, 1.0f, 1.0f, 1.1375361376887123f,
                              1.0f, 1.0f, 1.0f, 1.0f};

    const int b = blockIdx.x * BLK + threadIdx.x;
    float per = 0.0f;
    if (b < B) {
        const float*  tb = target + (size_t)b * 17;
        const float*  mb = mask   + (size_t)b * 17;
        const int*    ib = ind    + (size_t)b * 17;
        const float2* gb = (const float2*)(gt2d + (size_t)b * 34);
        const float*  ob = out_hm + (size_t)b * 4096;

        // Long-latency scattered gathers first (14 independent loads).
        int idx[17];
        #pragma unroll
        for (int k = 0; k < 14; ++k) idx[jl[k]] = ib[jl[k]];
        float pr[17];
        #pragma unroll
        for (int k = 0; k < 14; ++k) pr[jl[k]] = ob[idx[jl[k]]];

        float t[17], gx[17], gy[17];
        #pragma unroll
        for (int k = 0; k < 14; ++k) t[jl[k]] = tb[jl[k]];
        #pragma unroll
        for (int k = 0; k < 14; ++k) {
            float2 g = gb[jl[k]];
            gx[jl[k]] = g.x; gy[jl[k]] = g.y;
        }
        float msum = 0.0f;
        #pragma unroll
        for (int j = 0; j < 17; ++j) msum += mb[j];

        float num[4] = {0,0,0,0}, sl[4] = {0,0,0,0};
        float l[12];
        bool  vis[12];
        #pragma unroll
        for (int k = 0; k < 12; ++k) {
            const int a = id1[k], c = id2[k];
            const bool v = (t[a] > 0.5f) && (t[c] > 0.5f);
            const float dx = gx[a] - gx[c];
            const float dy = gy[a] - gy[c];
            const float dp = pr[a] - pr[c];
            const float d2 = dx*dx + dy*dy + dp*dp;
            const float lv = v ? sqrtf(d2) * wbone[k] : 0.0f;
            vis[k] = v; l[k] = lv;
            num[gid[k]] += v ? 1.0f : 0.0f;
            sl[gid[k]]  += lv;
        }
        float E[4], dn[4];
        #pragma unroll
        for (int g = 0; g < 4; ++g) { dn[g] = fmaxf(num[g], 1.0f); E[g] = sl[g] / dn[g]; }
        #pragma unroll
        for (int k = 0; k < 12; ++k) {
            if (vis[k] && l[k] > 0.0f) {
                const float d = l[k] - E[gid[k]];
                per += d * d / (2.0f * dn[gid[k]]);
            }
        }
        if (msum != 0.0f) per = 0.0f;   // active = (mask.sum == 0)
    }

    // single-wave block: pure shuffle reduction, no LDS, no barrier
    #pragma unroll
    for (int off = 32; off > 0; off >>= 1) per += __shfl_down(per, off, 64);
    if (threadIdx.x == 0) partial[blockIdx.x] = per;
}

__global__ __launch_bounds__(64) void bone_finalize(
    const float* __restrict__ partial, int n,
    float* __restrict__ out, float invB)
{
    float s = 0.0f;
    for (int i = threadIdx.x; i < n; i += 64) s += partial[i];
    #pragma unroll
    for (int off = 32; off > 0; off >>= 1) s += __shfl_down(s, off, 64);
    if (threadIdx.x == 0) out[0] = s * invB;   // _VAR_WEIGHT == 1.0
}

extern "C" void kernel_launch(void* const* d_in, const int* in_sizes, int n_in,
                              void* d_out, int out_size, void* d_ws, size_t ws_size,
                              hipStream_t stream)
{
    const float* output = (const float*)d_in[0];
    const float* mask   = (const float*)d_in[1];
    const int*   ind    = (const int*)  d_in[2];
    const float* target = (const float*)d_in[3];
    const float* gt2d   = (const float*)d_in[4];

    const int B    = in_sizes[1] / 17;        // mask is [B,17]
    const int nblk = (B + BLK - 1) / BLK;     // 128 blocks for B=8192

    float* partial = (float*)d_ws;            // nblk floats of scratch

    bone_partial<<<nblk, BLK, 0, stream>>>(output, mask, ind, target, gt2d, partial, B);
    bone_finalize<<<1, 64, 0, stream>>>(partial, nblk, (float*)d_out, 1.0f / (float)B);
}